// Round 14
// baseline (797.535 us; speedup 1.0000x reference)
//
#include <hip/hip_runtime.h>
#include <math.h>

#define D 512
#define HEADS 8
#define NLAYER 6
#define LSEQ 1024
#define BATCH 4
#define DKH 64
#define MTOK (BATCH*LSEQ)   // 4096 tokens
#define EPS 1e-5f
#define EMB_SCALE 22.627416997969522f  // sqrt(512)
#define INV_SCALE 0.125f               // 1/sqrt(64)

typedef __attribute__((ext_vector_type(8))) __bf16 bf16x8;
typedef __attribute__((ext_vector_type(4))) float f32x4;

__device__ __forceinline__ unsigned short f2bf(float x) {
    union { float f; unsigned u; } v; v.f = x;
    unsigned r = (v.u + 0x7FFFu + ((v.u >> 16) & 1u)) >> 16;
    return (unsigned short)r;
}
__device__ __forceinline__ unsigned pack2(float a, float b) {
    return (unsigned)f2bf(a) | ((unsigned)f2bf(b) << 16);
}
__device__ __forceinline__ void gl_lds16(const unsigned short* g, unsigned short* l) {
    __builtin_amdgcn_global_load_lds(
        (const __attribute__((address_space(1))) unsigned*)g,
        (__attribute__((address_space(3))) unsigned*)l, 16, 0, 0);
}
// asm 16B global load (attn): volatile asm cannot be sunk -> pipeline holds.
__device__ __forceinline__ void gload16(bf16x8& d, const unsigned short* p) {
    asm volatile("global_load_dwordx4 %0, %1, off" : "=v"(d) : "v"(p));
}

// ---------------- prep: weights (gamma-folded) + LN-fold vectors + embed ----
// R14 algebraic LN fold: h@W^T = inv*(x@(W.g)^T) - inv*m*(g@W^T) + (beta@W^T).
// prep: (a) converts weights to bf16 with gamma folded into Wqkv/W1 columns,
// (b) computes vg = g@W^T and vb = beta@W^T + bias per output (wave-dots),
// (c) zeroes the 12 atomic stat buffers, (d) embed writes x fp32 + xb bf16 +
// layer-0 ln1 stats. Consumers (QKV/FFN1) read RAW xb with the unchanged
// global_load_lds pipeline (R8's fatal flaws avoided); producers (Wo/FFN2)
// emit stats + xb from their epilogue registers.
__global__ __launch_bounds__(256) void prep_kernel(
    const int* __restrict__ tokens, const float* __restrict__ emb,
    const float* __restrict__ Wq, const float* __restrict__ bq,
    const float* __restrict__ Wkv, const float* __restrict__ bkv,
    const float* __restrict__ Wo, const float* __restrict__ W1,
    const float* __restrict__ b1, const float* __restrict__ W2,
    const float* __restrict__ ln1g, const float* __restrict__ ln1b,
    const float* __restrict__ ln2g, const float* __restrict__ ln2b,
    unsigned short* __restrict__ wl, float* __restrict__ vecg,
    float* __restrict__ vecb, float* __restrict__ stats,
    float* __restrict__ x, unsigned short* __restrict__ xb)
{
    const int bid = blockIdx.x;
    const int tid = threadIdx.x;
    if (bid < 9216) {                       // weight conversion + gamma fold
        const int l = bid / 1536;
        const int e = (bid - l * 1536) * 2048 + tid * 8;
        const float* src;
        if      (e < 262144)  src = Wq  + (size_t)l * 262144  + e;
        else if (e < 786432)  src = Wkv + (size_t)l * 524288  + (e - 262144);
        else if (e < 1048576) src = Wo  + (size_t)l * 262144  + (e - 786432);
        else if (e < 2097152) src = W1  + (size_t)l * 1048576 + (e - 1048576);
        else                  src = W2  + (size_t)l * 1048576 + (e - 2097152);
        float4 a = *(const float4*)src;
        float4 b = *(const float4*)(src + 4);
        const float* gp = nullptr;
        if (e < 786432)                          gp = ln1g + l * 512;  // Wq/Wkv
        else if (e >= 1048576 && e < 2097152)    gp = ln2g + l * 512;  // W1
        if (gp) {
            int cb = e & 511;   // all region bases are multiples of 512
            a.x *= gp[cb];     a.y *= gp[cb + 1]; a.z *= gp[cb + 2]; a.w *= gp[cb + 3];
            b.x *= gp[cb + 4]; b.y *= gp[cb + 5]; b.z *= gp[cb + 6]; b.w *= gp[cb + 7];
        }
        uint4 o;
        o.x = pack2(a.x, a.y); o.y = pack2(a.z, a.w);
        o.z = pack2(b.x, b.y); o.w = pack2(b.z, b.w);
        *(uint4*)(wl + (size_t)l * 3145728 + e) = o;
    } else if (bid < 14592) {               // vg/vb wave-dots (21504 outputs)
        const int lane = tid & 63, wave = tid >> 6;
        const int out = (bid - 9216) * 4 + wave;
        const float *wrow, *g, *bl;
        float bias;
        if (out < 9216) {                   // QKV space
            int l = out / 1536, n = out - l * 1536;
            wrow = (n < 512) ? Wq + (size_t)l * 262144 + (size_t)n * 512
                             : Wkv + (size_t)l * 524288 + (size_t)(n - 512) * 512;
            g = ln1g + l * 512; bl = ln1b + l * 512;
            bias = (n < 512) ? bq[l * 512 + n] : bkv[l * 1024 + (n - 512)];
        } else {                            // FFN1 space
            int o2 = out - 9216;
            int l = o2 / 2048, n = o2 - l * 2048;
            wrow = W1 + (size_t)l * 1048576 + (size_t)n * 512;
            g = ln2g + l * 512; bl = ln2b + l * 512;
            bias = b1[l * 2048 + n];
        }
        const float* wp = wrow + lane * 8;
        float4 w0 = *(const float4*)wp,       w1 = *(const float4*)(wp + 4);
        float4 g0 = *(const float4*)(g + lane * 8),  g1 = *(const float4*)(g + lane * 8 + 4);
        float4 c0 = *(const float4*)(bl + lane * 8), c1 = *(const float4*)(bl + lane * 8 + 4);
        float sg = w0.x*g0.x + w0.y*g0.y + w0.z*g0.z + w0.w*g0.w
                 + w1.x*g1.x + w1.y*g1.y + w1.z*g1.z + w1.w*g1.w;
        float sb = w0.x*c0.x + w0.y*c0.y + w0.z*c0.z + w0.w*c0.w
                 + w1.x*c1.x + w1.y*c1.y + w1.z*c1.z + w1.w*c1.w;
#pragma unroll
        for (int off = 32; off; off >>= 1) {
            sg += __shfl_xor(sg, off, 64);
            sb += __shfl_xor(sb, off, 64);
        }
        if (lane == 0) { vecg[out] = sg; vecb[out] = sb + bias; }
    } else if (bid < 14688) {               // zero stats[8192 .. 106496)
        int i = (bid - 14592) * 1024 + tid * 4;
        *(float4*)&stats[8192 + i] = (float4){0.f, 0.f, 0.f, 0.f};
    } else {                                // embed + PE + xb + ln1[0] stats
        int row = (bid - 14688) * 4 + (tid >> 6);
        int lane = tid & 63;
        int pos = row & (LSEQ - 1);
        int tok = tokens[row];
        int c = lane * 8;
        const float* ep = emb + (size_t)tok * D + c;
        float4 e0 = *(const float4*)ep;
        float4 e1 = *(const float4*)(ep + 4);
        float v[8] = {e0.x, e0.y, e0.z, e0.w, e1.x, e1.y, e1.z, e1.w};
        float s = 0.f, ss = 0.f;
#pragma unroll
        for (int i = 0; i < 8; ++i) {
            int col = c + i, ii = col & ~1;
            float dv = expf(-(float)ii * (9.210340371976184f / (float)D));
            float a = (float)pos * dv;
            float pe = (col & 1) ? cosf(a) : sinf(a);
            v[i] = v[i] * EMB_SCALE + pe;
            s += v[i]; ss += v[i] * v[i];
        }
        float4 r0; r0.x = v[0]; r0.y = v[1]; r0.z = v[2]; r0.w = v[3];
        float4 r1; r1.x = v[4]; r1.y = v[5]; r1.z = v[6]; r1.w = v[7];
        *(float4*)(x + (size_t)row * D + c) = r0;
        *(float4*)(x + (size_t)row * D + c + 4) = r1;
        uint4 ob;
        ob.x = pack2(v[0], v[1]); ob.y = pack2(v[2], v[3]);
        ob.z = pack2(v[4], v[5]); ob.w = pack2(v[6], v[7]);
        *(uint4*)(xb + (size_t)row * D + c) = ob;
#pragma unroll
        for (int off = 1; off < 64; off <<= 1) {
            s  += __shfl_xor(s,  off, 64);
            ss += __shfl_xor(ss, off, 64);
        }
        if (lane == 0) { stats[row * 2] = s; stats[row * 2 + 1] = ss; }
    }
}

// ---------------- bf16 MFMA GEMM: acc = A(bf16 MxK) @ W(bf16 NxK)^T ----------------
// 2-phase double-buffered pipeline, XOR-swizzled LDS (R10 measured-best core,
// UNCHANGED). R14 epilogues:
//  OMODE 0: C fp32 = acc+bias+X; also writes xb bf16 and atomically
//           accumulates row {sum,sumsq} into statsOut (next LN consumer).
//  OMODE 1: relu LN-fold: val = relu(inv*(acc - m*vg[c]) + vb[c]).
//  OMODE 2: QKV LN-fold: val = inv*(acc - m*vg[c]) + vb[c]; fragment-linear
//           Q (scaled) / K / V outputs for attn.
template<int OMODE, int BM, int BN, int BK>
__global__ __launch_bounds__(256) void gemm_bf16(
    const unsigned short* __restrict__ A, const unsigned short* __restrict__ W,
    const float* __restrict__ bias, const float* __restrict__ X,
    void* __restrict__ C, void* __restrict__ C2, void* __restrict__ C3,
    const float* __restrict__ lstats, const float* __restrict__ vg,
    const float* __restrict__ vb, float* __restrict__ statsOut,
    unsigned short* __restrict__ xbOut,
    int M, int N, int K)
{
    constexpr int WM = BM / 64;        // 2 or 1
    constexpr int WN = 4 / WM;         // 2 or 4
    constexpr int NI = BN / (WN * 16); // 16-col frags per wave
    constexpr int CPB = BK / 8;        // 8-short chunks per row
    constexpr int RPP = 2048 / BK;     // rows covered per 256-thread pass
    __shared__ __align__(16) unsigned short As[2][BM * BK];
    __shared__ __align__(16) unsigned short Bs[2][BN * BK];
    const int tid = threadIdx.x;
    const int wave = tid >> 6, lane = tid & 63;
    const int quad = lane >> 4, l16 = lane & 15;
    const int wm = wave / WN, wn = wave % WN;
    const int bm = blockIdx.y * BM, bn = blockIdx.x * BN;

    const int rS  = tid / CPB;
    const int ch  = tid % CPB;
    const int csw = ((ch ^ (rS & 7)) << 3);
    const unsigned short* Asrc = A + (size_t)(bm + rS) * K + csw;
    const unsigned short* Bsrc = W + (size_t)(bn + rS) * K + csw;

    f32x4 acc[4][NI];
#pragma unroll
    for (int mi = 0; mi < 4; ++mi)
#pragma unroll
        for (int ni = 0; ni < NI; ++ni) acc[mi][ni] = (f32x4){0.f, 0.f, 0.f, 0.f};

    const int nt = K / BK;

    // prologue: stage tile 0
#pragma unroll
    for (int i = 0; i < BM / RPP; ++i)
        gl_lds16(Asrc + (size_t)(i * RPP) * K, &As[0][i * 2048 + tid * 8]);
#pragma unroll
    for (int i = 0; i < BN / RPP; ++i)
        gl_lds16(Bsrc + (size_t)(i * RPP) * K, &Bs[0][i * 2048 + tid * 8]);
    __syncthreads();

    for (int t = 0; t < nt; ++t) {
        const int cur = t & 1;
        if (t + 1 < nt) {
            const int k0 = (t + 1) * BK;
#pragma unroll
            for (int i = 0; i < BM / RPP; ++i)
                gl_lds16(Asrc + (size_t)(i * RPP) * K + k0, &As[cur ^ 1][i * 2048 + tid * 8]);
#pragma unroll
            for (int i = 0; i < BN / RPP; ++i)
                gl_lds16(Bsrc + (size_t)(i * RPP) * K + k0, &Bs[cur ^ 1][i * 2048 + tid * 8]);
        }
#pragma unroll
        for (int kc = 0; kc < BK / 32; ++kc) {
            const int gch = (kc << 2) | quad;   // global col chunk this quad wants
            bf16x8 af[4], bfr[NI];
#pragma unroll
            for (int mi = 0; mi < 4; ++mi) {
                const int ra = wm * 64 + mi * 16 + l16;
                af[mi] = *(const bf16x8*)&As[cur][ra * BK + ((gch ^ (ra & 7)) << 3)];
            }
#pragma unroll
            for (int ni = 0; ni < NI; ++ni) {
                const int rb = wn * (BN / WN) + ni * 16 + l16;
                bfr[ni] = *(const bf16x8*)&Bs[cur][rb * BK + ((gch ^ (rb & 7)) << 3)];
            }
#pragma unroll
            for (int mi = 0; mi < 4; ++mi)
#pragma unroll
                for (int ni = 0; ni < NI; ++ni)
                    acc[mi][ni] = __builtin_amdgcn_mfma_f32_16x16x32_bf16(
                        af[mi], bfr[ni], acc[mi][ni], 0, 0, 0);
        }
        __syncthreads();   // drains vmcnt(0): next tile landed, cur reads done
    }

    const int er = bm + wm * 64;
    const int ec = bn + wn * (BN / WN);

    if (OMODE == 0) {
        float* Cf = (float*)C;
#pragma unroll
        for (int mi = 0; mi < 4; ++mi)
#pragma unroll
            for (int r = 0; r < 4; ++r) {
                int m = er + mi * 16 + quad * 4 + r;
                float s = 0.f, sq = 0.f;
#pragma unroll
                for (int ni = 0; ni < NI; ++ni) {
                    int c = ec + ni * 16 + l16;
                    float val = acc[mi][ni][r] + bias[c] + X[(size_t)m * N + c];
                    Cf[(size_t)m * N + c] = val;
                    xbOut[(size_t)m * N + c] = f2bf(val);
                    s += val; sq += val * val;
                }
#pragma unroll
                for (int off = 1; off < 16; off <<= 1) {
                    s  += __shfl_xor(s,  off, 64);
                    sq += __shfl_xor(sq, off, 64);
                }
                if (l16 == 0) {
                    atomicAdd(&statsOut[(size_t)m * 2],     s);
                    atomicAdd(&statsOut[(size_t)m * 2 + 1], sq);
                }
            }
    } else {
        // per-row mean/inv from producer stats
        float mvv[4][4], ivv[4][4];
#pragma unroll
        for (int mi = 0; mi < 4; ++mi)
#pragma unroll
            for (int r = 0; r < 4; ++r) {
                int m = er + mi * 16 + quad * 4 + r;
                float sm = lstats[(size_t)m * 2];
                float sq = lstats[(size_t)m * 2 + 1];
                float mn = sm * (1.0f / D);
                mvv[mi][r] = mn;
                ivv[mi][r] = rsqrtf(sq * (1.0f / D) - mn * mn + EPS);
            }
        if (OMODE == 1) {
            unsigned short* Cb = (unsigned short*)C;
#pragma unroll
            for (int ni = 0; ni < NI; ++ni) {
                int c = ec + ni * 16 + l16;
                float vgc = vg[c], vbc = vb[c];
#pragma unroll
                for (int mi = 0; mi < 4; ++mi)
#pragma unroll
                    for (int r = 0; r < 4; ++r) {
                        int m = er + mi * 16 + quad * 4 + r;
                        float val = ivv[mi][r] * (acc[mi][ni][r] - mvv[mi][r] * vgc) + vbc;
                        Cb[(size_t)m * N + c] = f2bf(fmaxf(val, 0.f));
                    }
            }
        } else {
            if (bn < 512) {            // Q (scaled), fragment-linear
                unsigned short* Qp = (unsigned short*)C;
#pragma unroll
                for (int ni = 0; ni < NI; ++ni) {
                    int c = ec + ni * 16 + l16;
                    float vgc = vg[c], vbc = vb[c];
                    int hh = c >> 6, dd = c & 63;
                    size_t cbase = (size_t)(dd >> 5) * 512 + (size_t)((dd >> 3) & 3) * 128 + (dd & 7);
#pragma unroll
                    for (int mi = 0; mi < 4; ++mi)
#pragma unroll
                        for (int r = 0; r < 4; ++r) {
                            int m = er + mi * 16 + quad * 4 + r;
                            int b = m >> 10, t = m & 1023;
                            float val = ivv[mi][r] * (acc[mi][ni][r] - mvv[mi][r] * vgc) + vbc;
                            Qp[(size_t)(b * 8 + hh) * 65536 + (size_t)(t >> 4) * 1024
                               + cbase + (size_t)(t & 15) * 8] = f2bf(val * INV_SCALE);
                        }
                }
            } else if (bn < 1024) {    // K, fragment-linear
                unsigned short* Kp = (unsigned short*)C2;
#pragma unroll
                for (int ni = 0; ni < NI; ++ni) {
                    int c = ec + ni * 16 + l16;
                    float vgc = vg[c], vbc = vb[c];
                    int c2 = c - 512;
                    int hh = c2 >> 6, dd = c2 & 63;
                    size_t cbase = (size_t)(dd >> 5) * 512 + (size_t)((dd >> 3) & 3) * 128 + (dd & 7);
#pragma unroll
                    for (int mi = 0; mi < 4; ++mi)
#pragma unroll
                        for (int r = 0; r < 4; ++r) {
                            int m = er + mi * 16 + quad * 4 + r;
                            int b = m >> 10, t = m & 1023;
                            float val = ivv[mi][r] * (acc[mi][ni][r] - mvv[mi][r] * vgc) + vbc;
                            Kp[(size_t)(b * 8 + hh) * 65536 + (size_t)(t >> 4) * 1024
                               + cbase + (size_t)(t & 15) * 8] = f2bf(val);
                        }
                }
            } else {                   // V, fragment-linear (transposed consumption)
                unsigned short* Vp = (unsigned short*)C3;
#pragma unroll
                for (int ni = 0; ni < NI; ++ni) {
                    int c = ec + ni * 16 + l16;
                    float vgc = vg[c], vbc = vb[c];
                    int c2 = c - 1024;
                    int hh = c2 >> 6, dd = c2 & 63;
                    size_t dbase = (size_t)(dd >> 4) * 16384 + (size_t)(dd & 15) * 8;
#pragma unroll
                    for (int mi = 0; mi < 4; ++mi) {
                        int t0 = er + mi * 16 + quad * 4;
                        int b = t0 >> 10, tt = t0 & 1023;
                        ushort4 o;
                        o.x = f2bf(ivv[mi][0] * (acc[mi][ni][0] - mvv[mi][0] * vgc) + vbc);
                        o.y = f2bf(ivv[mi][1] * (acc[mi][ni][1] - mvv[mi][1] * vgc) + vbc);
                        o.z = f2bf(ivv[mi][2] * (acc[mi][ni][2] - mvv[mi][2] * vgc) + vbc);
                        o.w = f2bf(ivv[mi][3] * (acc[mi][ni][3] - mvv[mi][3] * vgc) + vbc);
                        *(ushort4*)(Vp + (size_t)(b * 8 + hh) * 65536 + dbase
                                    + (size_t)(tt >> 5) * 512
                                    + (size_t)((tt >> 3) & 3) * 128 + (tt & 7)) = o;
                    }
                }
            }
        }
    }
}

// ---------------- flash attention: split-K, QROWS=32 per block (R10 exact) ----
__global__ __launch_bounds__(256, 1) void attn_mfma(
    const unsigned short* __restrict__ Qb, const unsigned short* __restrict__ Kb,
    const unsigned short* __restrict__ Vt, unsigned short* __restrict__ av)
{
    __shared__ float Ol[4][32][68];   // [wave][q][d] fp32 partial O (+pad)
    __shared__ float Ls[4][32];       // [wave][q] partial denominators
    const int tid = threadIdx.x;
    const int wave = tid >> 6, lane = tid & 63;
    const int quad = lane >> 4, l16 = lane & 15;
    const int bh = blockIdx.x & 31;          // xcd = bh % 8 -> K/V L2-resident per XCD
    const int b = bh >> 3, h = bh & 7;
    const int q0 = (blockIdx.x >> 5) * 32;   // 32 q-tiles of 32 rows

    const unsigned short* qp = Qb + (size_t)bh * 65536 + (size_t)(q0 >> 4) * 1024 + lane * 8;
    const unsigned short* kbase = Kb + (size_t)bh * 65536 + lane * 8;
    const unsigned short* vbase = Vt + (size_t)bh * 65536 + lane * 8;

    // bpermute byte addresses: pull from quad (2q)&3 / (2q+1)&3 at same l16
    const int sA  = ((((2 * quad) & 3) << 4) + l16) << 2;
    const int sB2 = ((((2 * quad + 1) & 3) << 4) + l16) << 2;

    f32x4 o[2][4];
#pragma unroll
    for (int qs = 0; qs < 2; ++qs)
#pragma unroll
        for (int nf = 0; nf < 4; ++nf) o[qs][nf] = (f32x4){0.f, 0.f, 0.f, 0.f};
    float lp[2] = {0.f, 0.f};   // per-lane partial column (=query) sums

    const int j0 = wave * 256;

    // ---- prologue: issue Q (4) + buffer0 K/V (16) loads; 20 in flight ----
    bf16x8 qf[2][2];
    gload16(qf[0][0], qp);
    gload16(qf[0][1], qp + 512);
    gload16(qf[1][0], qp + 1024);
    gload16(qf[1][1], qp + 1536);

    bf16x8 kc[2][8], vf[2][8];
#pragma unroll
    for (int nf = 0; nf < 4; ++nf) {
        gload16(kc[0][2 * nf],     kbase + (size_t)j0 * 64 + nf * 1024);
        gload16(kc[0][2 * nf + 1], kbase + (size_t)j0 * 64 + nf * 1024 + 512);
        gload16(vf[0][2 * nf],     vbase + (size_t)j0 * 16 + nf * 16384);
        gload16(vf[0][2 * nf + 1], vbase + (size_t)j0 * 16 + nf * 16384 + 512);
    }

#pragma unroll
    for (int it = 0; it < 4; ++it) {
        const int cur = it & 1, nxt = cur ^ 1;
        // ---- issue next tile's 16 loads BEFORE waiting on current ----
        if (it < 3) {
            const int jn = j0 + (it + 1) * 64;
#pragma unroll
            for (int nf = 0; nf < 4; ++nf) {
                gload16(kc[nxt][2 * nf],     kbase + (size_t)jn * 64 + nf * 1024);
                gload16(kc[nxt][2 * nf + 1], kbase + (size_t)jn * 64 + nf * 1024 + 512);
                gload16(vf[nxt][2 * nf],     vbase + (size_t)jn * 16 + nf * 16384);
                gload16(vf[nxt][2 * nf + 1], vbase + (size_t)jn * 16 + nf * 16384 + 512);
            }
        }
        // ---- counted wait: current buffer (+Q at it=0) done, next 16 in flight ----
        if (it < 3) asm volatile("s_waitcnt vmcnt(16)" ::: "memory");
        else        asm volatile("s_waitcnt vmcnt(0)"  ::: "memory");
        __builtin_amdgcn_sched_barrier(0);
        // ---- S^T tiles (row=key, col=query), exp, pack — per (nf, qs) ----
        unsigned pk01[2][4], pk23[2][4];
#pragma unroll
        for (int nf = 0; nf < 4; ++nf)
#pragma unroll
            for (int qs = 0; qs < 2; ++qs) {
                f32x4 z = {0.f, 0.f, 0.f, 0.f};
                z = __builtin_amdgcn_mfma_f32_16x16x32_bf16(kc[cur][2 * nf], qf[qs][0], z, 0, 0, 0);
                z = __builtin_amdgcn_mfma_f32_16x16x32_bf16(kc[cur][2 * nf + 1], qf[qs][1], z, 0, 0, 0);
                float p0 = __expf(z[0]);
                float p1 = __expf(z[1]);
                float p2 = __expf(z[2]);
                float p3 = __expf(z[3]);
                lp[qs] += (p0 + p1) + (p2 + p3);
                pk01[qs][nf] = pack2(p0, p1);
                pk23[qs][nf] = pack2(p2, p3);
            }
        // ---- register-only C->A transform (validated), per q-subtile ----
#pragma unroll
        for (int qs = 0; qs < 2; ++qs) {
            union PU { unsigned d[4]; bf16x8 v; } f0, f1;
            unsigned a0, a1;
            a0 = (unsigned)__builtin_amdgcn_ds_bpermute(sA,  (int)pk01[qs][0]);
            a1 = (unsigned)__builtin_amdgcn_ds_bpermute(sA,  (int)pk01[qs][1]);
            f0.d[0] = (quad < 2) ? a0 : a1;
            a0 = (unsigned)__builtin_amdgcn_ds_bpermute(sA,  (int)pk23[qs][0]);
            a1 = (unsigned)__builtin_amdgcn_ds_bpermute(sA,  (int)pk23[qs][1]);
            f0.d[1] = (quad < 2) ? a0 : a1;
            a0 = (unsigned)__builtin_amdgcn_ds_bpermute(sB2, (int)pk01[qs][0]);
            a1 = (unsigned)__builtin_amdgcn_ds_bpermute(sB2, (int)pk01[qs][1]);
            f0.d[2] = (quad < 2) ? a0 : a1;
            a0 = (unsigned)__builtin_amdgcn_ds_bpermute(sB2, (int)pk23[qs][0]);
            a1 = (unsigned)__builtin_amdgcn_ds_bpermute(sB2, (int)pk23[qs][1]);
            f0.d[3] = (quad < 2) ? a0 : a1;
            a0 = (unsigned)__builtin_amdgcn_ds_bpermute(sA,  (int)pk01[qs][2]);
            a1 = (unsigned)__builtin_amdgcn_ds_bpermute(sA,  (int)pk01[qs][3]);
            f1.d[0] = (quad < 2) ? a0 : a1;
            a0 = (unsigned)__builtin_amdgcn_ds_bpermute(sA,  (int)pk23[qs][2]);
            a1 = (unsigned)__builtin_amdgcn_ds_bpermute(sA,  (int)pk23[qs][3]);
            f1.d[1] = (quad < 2) ? a0 : a1;
            a0 = (unsigned)__builtin_amdgcn_ds_bpermute(sB2, (int)pk01[qs][2]);
            a1 = (unsigned)__builtin_amdgcn_ds_bpermute(sB2, (int)pk01[qs][3]);
            f1.d[2] = (quad < 2) ? a0 : a1;
            a0 = (unsigned)__builtin_amdgcn_ds_bpermute(sB2, (int)pk23[qs][2]);
            a1 = (unsigned)__builtin_amdgcn_ds_bpermute(sB2, (int)pk23[qs][3]);
            f1.d[3] = (quad < 2) ? a0 : a1;
            // ---- O += P.V ----
#pragma unroll
            for (int nf = 0; nf < 4; ++nf) {
                o[qs][nf] = __builtin_amdgcn_mfma_f32_16x16x32_bf16(f0.v, vf[cur][2 * nf], o[qs][nf], 0, 0, 0);
                o[qs][nf] = __builtin_amdgcn_mfma_f32_16x16x32_bf16(f1.v, vf[cur][2 * nf + 1], o[qs][nf], 0, 0, 0);
            }
        }
    }
    // ---- write per-wave partials to LDS ----
#pragma unroll
    for (int qs = 0; qs < 2; ++qs)
#pragma unroll
        for (int nf = 0; nf < 4; ++nf)
#pragma unroll
            for (int r = 0; r < 4; ++r)
                Ol[wave][qs * 16 + quad * 4 + r][nf * 16 + l16] = o[qs][nf][r];
#pragma unroll
    for (int qs = 0; qs < 2; ++qs) {
        float ts = lp[qs];
        ts += __shfl_xor(ts, 16, 64);
        ts += __shfl_xor(ts, 32, 64);
        if (quad == 0) Ls[wave][qs * 16 + l16] = ts;
    }
    __syncthreads();
    // ---- combine: wave w handles d-frag nf=w, 32 q rows ----
#pragma unroll
    for (int half = 0; half < 2; ++half)
#pragma unroll
        for (int r = 0; r < 4; ++r) {
            int qq = half * 16 + quad * 4 + r;
            float denom = Ls[0][qq] + Ls[1][qq] + Ls[2][qq] + Ls[3][qq];
            float v = Ol[0][qq][wave * 16 + l16] + Ol[1][qq][wave * 16 + l16]
                    + Ol[2][qq][wave * 16 + l16] + Ol[3][qq][wave * 16 + l16];
            int q = q0 + qq;
            av[((size_t)(b * 1024 + q)) * D + h * 64 + wave * 16 + l16] =
                f2bf(v / denom);
        }
}

// ---------------- classifier ----------------
__global__ __launch_bounds__(256) void cls_kernel(
    const float* __restrict__ x, const float* __restrict__ Wc,
    const float* __restrict__ bc, float* __restrict__ out)
{
    int lane = threadIdx.x & 63;
    int row = blockIdx.x * 4 + (threadIdx.x >> 6);
    const float* xr = x + (size_t)row * D + lane * 8;
    float4 v0 = *(const float4*)xr;
    float4 v1 = *(const float4*)(xr + 4);
    float acc[10];
#pragma unroll
    for (int c = 0; c < 10; ++c) {
        const float* wr = Wc + c * D + lane * 8;
        float4 w0 = *(const float4*)wr;
        float4 w1 = *(const float4*)(wr + 4);
        acc[c] = v0.x*w0.x + v0.y*w0.y + v0.z*w0.z + v0.w*w0.w
               + v1.x*w1.x + v1.y*w1.y + v1.z*w1.z + v1.w*w1.w;
    }
#pragma unroll
    for (int c = 0; c < 10; ++c)
#pragma unroll
        for (int off = 32; off; off >>= 1) acc[c] += __shfl_xor(acc[c], off, 64);
    if (lane == 0) {
#pragma unroll
        for (int c = 0; c < 10; ++c) out[(size_t)row * 10 + c] = acc[c] + bc[c];
    }
}

extern "C" void kernel_launch(void* const* d_in, const int* in_sizes, int n_in,
                              void* d_out, int out_size, void* d_ws, size_t ws_size,
                              hipStream_t stream)
{
    const int*   tokens = (const int*)  d_in[0];
    const float* emb    = (const float*)d_in[1];
    const float* Wq     = (const float*)d_in[2];
    const float* bq     = (const float*)d_in[3];
    const float* Wkv    = (const float*)d_in[4];
    const float* bkv    = (const float*)d_in[5];
    const float* Wo     = (const float*)d_in[6];
    const float* bo     = (const float*)d_in[7];
    const float* ln1g   = (const float*)d_in[8];
    const float* ln1b   = (const float*)d_in[9];
    const float* W1     = (const float*)d_in[10];
    const float* b1     = (const float*)d_in[11];
    const float* W2     = (const float*)d_in[12];
    const float* b2     = (const float*)d_in[13];
    const float* ln2g   = (const float*)d_in[14];
    const float* ln2b   = (const float*)d_in[15];
    const float* Wc     = (const float*)d_in[16];
    const float* bc     = (const float*)d_in[17];
    float* out = (float*)d_out;

    // workspace (~65 MB; harness poisons >=268MB per fillBuffer WRITE_SIZE):
    // x fp32 8MB | xb bf16 4MB | Qb 4 | Kb 4 | Vt 4 | avb 4 (f1b aliases Qb..)
    // | wl bf16 36MB | vecg/vecb 172KB | stats 416KB
    float* x  = (float*)d_ws;
    unsigned short* xb  = (unsigned short*)(x + (size_t)MTOK * D);
    unsigned short* Qb  = xb  + (size_t)MTOK * D;
    unsigned short* Kb  = Qb  + (size_t)32 * 1024 * 64;
    unsigned short* Vt  = Kb  + (size_t)32 * 1024 * 64;
    unsigned short* avb = Vt  + (size_t)32 * 1024 * 64;
    unsigned short* f1b = Qb;                              // [4096][2048] bf16 = 16 MB
    unsigned short* wl  = avb + (size_t)32 * 1024 * 64;    // all-layer bf16 weights (36 MB)
    float* vecg  = (float*)(wl + (size_t)6 * 3145728);     // 21504: g@W^T
    float* vecb  = vecg + 21504;                           // 21504: beta@W^T + bias
    float* stats = vecb + 21504;                           // 13 x [4096][2] row stats
    // stats: ln1[l] at stats+l*8192 (l=0 by prep-embed; l>=1 by FFN2 of l-1);
    // ln2[l] at stats+(7+l)*8192 (by Wo of l).

    const size_t oWo = 786432, oW1 = 1048576, oW2 = 2097152, LW = 3145728;

    prep_kernel<<<15712, 256, 0, stream>>>(
        tokens, emb, Wq, bq, Wkv, bkv, Wo, W1, b1, W2,
        ln1g, ln1b, ln2g, ln2b, wl, vecg, vecb, stats, x, xb);

    for (int l = 0; l < NLAYER; ++l) {
        const unsigned short* wll = wl + (size_t)l * LW;
        float* sl1  = stats + (size_t)l * 8192;
        float* sl1n = stats + (size_t)(l + 1) * 8192;
        float* sl2  = stats + (size_t)(7 + l) * 8192;
        // QKV with algebraic ln1 fold (A = raw xb)
        gemm_bf16<2,128,64,64><<<dim3(24, 32), 256, 0, stream>>>(
            xb, wll, nullptr, nullptr, Qb, Kb, Vt,
            sl1, vecg + l * 1536, vecb + l * 1536, nullptr, nullptr,
            MTOK, 1536, 512);
        attn_mfma<<<1024, 256, 0, stream>>>(Qb, Kb, Vt, avb);
        // Wo: x += av@Wo^T + bo; emits xb + ln2 stats
        gemm_bf16<0,64,64,128><<<dim3(8, 64), 256, 0, stream>>>(
            avb, wll + oWo, bo + l * D, x, x, nullptr, nullptr,
            nullptr, nullptr, nullptr, sl2, xb, MTOK, D, D);
        // FFN1 with algebraic ln2 fold (A = raw xb)
        gemm_bf16<1,128,128,64><<<dim3(16, 32), 256, 0, stream>>>(
            xb, wll + oW1, nullptr, nullptr, f1b, nullptr, nullptr,
            sl2, vecg + 9216 + l * 2048, vecb + 9216 + l * 2048, nullptr, nullptr,
            MTOK, 4 * D, D);
        // FFN2: x += f1b@W2^T + b2; emits xb + next ln1 stats
        gemm_bf16<0,64,64,128><<<dim3(8, 64), 256, 0, stream>>>(
            f1b, wll + oW2, b2 + l * D, x, x, nullptr, nullptr,
            nullptr, nullptr, nullptr, sl1n, xb, MTOK, D, 4 * D);
    }

    cls_kernel<<<MTOK / 4, 256, 0, stream>>>(x, Wc, bc, out);
}